// Round 7
// baseline (91.354 us; speedup 1.0000x reference)
//
#include <hip/hip_runtime.h>

// HMLoss: 4-region histogram-matching L1 loss, H=W=2048.
// Single image pass, block-specialized: blocks [0,256) build the src fine
// histogram (fake+mask_A), blocks [256,512) build the tar cdf histogram
// (ref_B+mask_B+mask_A for the ==11 bug term). Src fine hist is keyed by
// key = trunc(v) + cdfbin(v) with packed (N<<41 | S), S = v in exact 2^11
// fixed point. Loss from per-coarse-bin stats:
//   sum|v-t| over bin b = (t<=b) ? S-N*t : N*t-S   (exact integer).
// Extreme values (clamp pile-ups at v=0/255, ~16% each) use 8 per-lane alias
// slots merged before flush. Tar blocks keep 4 replicated histograms (one per
// 4-wave group) in the LDS that src-only `ns` would occupy.
//
// ws layout (8 flush copies):
//   [0, 393216)        u64 gNS[8][12][512]  src packed stats
//   [393216, 491520)   u64 gT [8][12][128]  tar hist, bins packed in pairs
//   [491520, 491528)   s64 acc              loss accumulator (2^11 fixed pt)

#define FACEA_BITS ((1u<<1)|(1u<<7)|(1u<<8)|(1u<<10)|(1u<<11)|(1u<<14))
#define FACEB_BITS ((1u<<1)|(1u<<7)|(1u<<8)|(1u<<10)|(1u<<14))
#define HAIR_BITS  (1u<<17)
#define EYEL_BITS  ((1u<<2)|(1u<<4))
#define EYER_BITS  ((1u<<3)|(1u<<5))

typedef unsigned long long u64;
typedef long long s64;

#define NSTRIDE 528   // 512 fine keys + 8 zero-aliases + 8 max-aliases
#define TSTRIDE 272   // 256 bins + 8 + 8
#define TREP    3264  // 12*TSTRIDE words per tar replica
#define M41 ((1ull << 41) - 1)
#define NSRC 256      // src blocks; tar blocks = [NSRC, 512)

__device__ __forceinline__ float denorm255(float x) {
  float t = (x + 1.0f) * 0.5f;
  t = fminf(fmaxf(t, 0.0f), 1.0f);
  return t * 255.0f;
}

// v >= 0 guaranteed: cast = trunc = floor; only upper clamp needed.
__device__ __forceinline__ int bin_of(float v) {
  int b = (int)(v * (256.0f / 255.0f));
  return b > 255 ? 255 : b;
}

__device__ __forceinline__ int regionA(unsigned bit) {
  if (bit & FACEA_BITS) return 0;
  if (bit & HAIR_BITS)  return 1;
  if (bit & EYEL_BITS)  return 2;
  if (bit & EYER_BITS)  return 3;
  return -1;
}
__device__ __forceinline__ int regionB(unsigned bit) {
  if (bit & FACEB_BITS) return 0;
  if (bit & HAIR_BITS)  return 1;
  if (bit & EYEL_BITS)  return 2;
  if (bit & EYER_BITS)  return 3;
  return -1;
}

__global__ __launch_bounds__(1024, 8) void hist_kernel(
    const float* __restrict__ fake, const float* __restrict__ refb,
    const int* __restrict__ ma, const int* __restrict__ mb,
    u64* __restrict__ gNS, u64* __restrict__ gT, int npix) {
  // 64000 B, unioned: src blocks use ns[12*NSTRIDE] u64 (50688 B);
  // tar blocks use 4 replicated hists [4][12*TSTRIDE] u32 (52224 B).
  __shared__ u64 lds64[8000];
  const int tid = threadIdx.x;
  const int lane8 = tid & 7;
  const int nq = npix >> 2;

  if (blockIdx.x < NSRC) {
    u64* ns = lds64;
    for (int i = tid; i < 12 * NSTRIDE; i += 1024) ns[i] = 0ull;
    __syncthreads();

    const float4* f0p = (const float4*)fake;
    const float4* f1p = (const float4*)(fake + npix);
    const float4* f2p = (const float4*)(fake + 2 * npix);
    const int4* map = (const int4*)ma;

    auto proc = [&](int4 m4, float4 f0, float4 f1, float4 f2) {
      int mm[4] = {m4.x, m4.y, m4.z, m4.w};
      float fa[3][4] = {{f0.x,f0.y,f0.z,f0.w},{f1.x,f1.y,f1.z,f1.w},
                        {f2.x,f2.y,f2.z,f2.w}};
#pragma unroll
      for (int k = 0; k < 4; ++k) {
        int sreg = regionA(1u << (mm[k] & 31));
        if (sreg >= 0) {
#pragma unroll
          for (int c = 0; c < 3; ++c) {
            float v = denorm255(fa[c][k]);
            int key = (int)v + bin_of(v);       // 2*c1 + (c2-c1)
            if (v == 0.0f) key = 512 + lane8;   // clamp pile-up aliases
            else if (v == 255.0f) key = 520 + lane8;
            u64 pack = (1ull << 41) | (u64)(unsigned)(v * 2048.0f);
            atomicAdd(&ns[(sreg * 3 + c) * NSTRIDE + key], pack);
          }
        }
      }
    };

    // 2 quads per iteration: 8 loads issued before any use (ILP).
    const int STR = NSRC * 2048;
    for (int q0 = blockIdx.x * 2048 + tid; q0 < nq; q0 += STR) {
      int q1 = q0 + 1024;
      bool has1 = q1 < nq;
      int4 mA = map[q0];
      float4 a0 = f0p[q0], a1 = f1p[q0], a2 = f2p[q0];
      int4 mB; float4 b0, b1, b2;
      if (has1) { mB = map[q1]; b0 = f0p[q1]; b1 = f1p[q1]; b2 = f2p[q1]; }
      proc(mA, a0, a1, a2);
      if (has1) proc(mB, b0, b1, b2);
    }
    __syncthreads();

    // merge aliases (v==0 -> fine key 0; v==255 -> key 510)
    if (tid < 24) {
      int rc = tid >> 1, hi = tid & 1;
      u64* base = &ns[rc * NSTRIDE];
      u64 s = 0;
      int a0 = 512 + hi * 8;
#pragma unroll
      for (int j = 0; j < 8; ++j) s += base[a0 + j];
      base[hi ? 510 : 0] += s;
    }
    __syncthreads();

    // flush ns: 8 copies, rotated start
    int copy = blockIdx.x & 7;
    int rot8 = ((blockIdx.x >> 3) & 63) * 8;
    for (int i = tid; i < 6144; i += 1024) {
      int rc = i >> 9;
      int key = ((i & 511) + rot8) & 511;
      u64 v = ns[rc * NSTRIDE + key];
      if (v) atomicAdd(&gNS[copy * 6144 + rc * 512 + key], v);
    }
  } else {
    unsigned* th0 = (unsigned*)lds64;
    unsigned* th = th0 + ((tid >> 8) & 3) * TREP;   // 4-wave-group replica
    for (int i = tid; i < 4 * TREP; i += 1024) th0[i] = 0u;
    __syncthreads();

    const float4* r0p = (const float4*)refb;
    const float4* r1p = (const float4*)(refb + npix);
    const float4* r2p = (const float4*)(refb + 2 * npix);
    const int4* map = (const int4*)ma;
    const int4* mbp = (const int4*)mb;

    auto proc = [&](int4 ma4, int4 mb4, float4 r0, float4 r1, float4 r2) {
      int mm[4] = {ma4.x, ma4.y, ma4.z, ma4.w};
      int bb[4] = {mb4.x, mb4.y, mb4.z, mb4.w};
      float rr[3][4] = {{r0.x,r0.y,r0.z,r0.w},{r1.x,r1.y,r1.z,r1.w},
                        {r2.x,r2.y,r2.z,r2.w}};
#pragma unroll
      for (int k = 0; k < 4; ++k) {
        int treg = regionB(1u << (bb[k] & 31));
        int fval = (treg == 0 ? 1 : 0) + ((mm[k] == 11) ? 1 : 0);
        if (fval > 0) {
          float fs = (float)fval;
#pragma unroll
          for (int c = 0; c < 3; ++c) {
            int bt = bin_of(denorm255(rr[c][k]) * fs);
            int idx = bt;
            if (bt == 0) idx = 256 + lane8;
            else if (bt == 255) idx = 264 + lane8;
            atomicAdd(&th[c * TSTRIDE + idx], 1u);
          }
        }
        if (treg >= 1) {
#pragma unroll
          for (int c = 0; c < 3; ++c) {
            int bt = bin_of(denorm255(rr[c][k]));
            int idx = bt;
            if (bt == 0) idx = 256 + lane8;
            else if (bt == 255) idx = 264 + lane8;
            atomicAdd(&th[(treg * 3 + c) * TSTRIDE + idx], 1u);
          }
        }
      }
    };

    const int STR = (512 - NSRC) * 2048;
    for (int q0 = (blockIdx.x - NSRC) * 2048 + tid; q0 < nq; q0 += STR) {
      int q1 = q0 + 1024;
      bool has1 = q1 < nq;
      int4 maA = map[q0], mbA = mbp[q0];
      float4 a0 = r0p[q0], a1 = r1p[q0], a2 = r2p[q0];
      int4 maB, mbB; float4 b0, b1, b2;
      if (has1) { maB = map[q1]; mbB = mbp[q1];
                  b0 = r0p[q1]; b1 = r1p[q1]; b2 = r2p[q1]; }
      proc(maA, mbA, a0, a1, a2);
      if (has1) proc(maB, mbB, b0, b1, b2);
    }
    __syncthreads();

    // merge 4 replicas into replica 0 (entry-wise, aliases included)
    for (int i = tid; i < TREP; i += 1024)
      th0[i] = th0[i] + th0[i + TREP] + th0[i + 2 * TREP] + th0[i + 3 * TREP];
    __syncthreads();

    // fold alias slots into bins 0/255
    if (tid < 24) {
      int rc = tid >> 1, hi = tid & 1;
      unsigned* base = &th0[rc * TSTRIDE];
      unsigned s = 0;
      int a0 = 256 + hi * 8;
#pragma unroll
      for (int j = 0; j < 8; ++j) s += base[a0 + j];
      base[hi ? 255 : 0] += s;
    }
    __syncthreads();

    // flush th as bin-pairs packed in u64 (no cross-carry: totals < 2^32)
    int copy = blockIdx.x & 7;
    int rot8 = ((blockIdx.x >> 3) & 63) * 8;
    for (int i = tid; i < 1536; i += 1024) {
      int rc = i >> 7;
      int p = ((i & 127) + rot8) & 127;
      unsigned lo = th0[rc * TSTRIDE + 2 * p];
      unsigned hi2 = th0[rc * TSTRIDE + 2 * p + 1];
      u64 w = (u64)lo | ((u64)hi2 << 32);
      if (w) atomicAdd(&gT[copy * 1536 + rc * 128 + p], w);
    }
  }
}

// 12 blocks, one per (region, channel). All staging parallel; exact integer
// tree totals; the two bit-faithful serial cumsums run LDS-only on different
// waves so they overlap.
__global__ __launch_bounds__(256) void cdf_loss_kernel(
    const u64* __restrict__ gNS, const u64* __restrict__ gT,
    u64* __restrict__ acc) {
  __shared__ unsigned Nf[512];
  __shared__ u64 Sf[512];
  __shared__ unsigned thA[256];
  __shared__ float hbD[256];
  __shared__ float dcdf[256];
  __shared__ float acdf[256];
  __shared__ unsigned rsum[512];   // [0..255] dst total, [256..511] tar total
  __shared__ s64 red[256];
  int rc = blockIdx.x;             // 0..11
  int t = threadIdx.x;

  {
    u64 a0 = 0, a1 = 0, w = 0;
#pragma unroll
    for (int cp = 0; cp < 8; ++cp) {
      a0 += gNS[cp * 6144 + rc * 512 + 2 * t];
      a1 += gNS[cp * 6144 + rc * 512 + 2 * t + 1];
      if (t < 128) w += gT[cp * 1536 + rc * 128 + t];
    }
    Nf[2 * t] = (unsigned)(a0 >> 41); Sf[2 * t] = a0 & M41;
    Nf[2 * t + 1] = (unsigned)(a1 >> 41); Sf[2 * t + 1] = a1 & M41;
    if (t < 128) {
      thA[2 * t] = (unsigned)(w & 0xFFFFFFFFull);
      thA[2 * t + 1] = (unsigned)(w >> 32);
    }
  }
  __syncthreads();

  // dst-CDF histogram bin t gathers fine keys 2t and 2t-1
  unsigned hD = Nf[2 * t] + (t ? Nf[2 * t - 1] : 0u);
  hbD[t] = (float)hD;
  rsum[t] = hD;
  rsum[256 + t] = thA[t];
  __syncthreads();
  for (int off = 128; off > 0; off >>= 1) {
    if (t < off) { rsum[t] += rsum[t + off]; rsum[256 + t] += rsum[256 + t + off]; }
    __syncthreads();
  }

  if (t == 0) {            // wave 0: dst cumsum (serial, LDS-only)
    float s = fmaxf((float)rsum[0], 1.0f);
    float run = 0.0f;
    for (int b = 0; b < 256; ++b) { run += hbD[b] / s; dcdf[b] = run; }
  }
  if (t == 64) {           // wave 1: tar cumsum, concurrent with wave 0
    float s = fmaxf((float)rsum[256], 1.0f);
    float run = 0.0f;
    for (int b = 0; b < 256; ++b) { run += (float)thA[b] / s; acdf[b] = run; }
  }
  __syncthreads();

  int tb;
  if (t == 0) tb = 0;
  else if (t == 255) tb = 255;
  else {
    float di = dcdf[t];
    tb = t;
    for (int j = 1; j < 256; ++j) {
      if (di >= acdf[j - 1] && di <= acdf[j]) { tb = j; break; }
    }
  }

  // exact loss contribution for coarse bin b = t (2^11 fixed point)
  unsigned Nb = Nf[2 * t] + Nf[2 * t + 1];
  u64 Sb = Sf[2 * t] + Sf[2 * t + 1];
  s64 nt = (s64)Nb * ((s64)tb << 11);
  s64 contrib = (tb <= t) ? ((s64)Sb - nt) : (nt - (s64)Sb);
  red[t] = contrib;
  __syncthreads();
  for (int off = 128; off > 0; off >>= 1) {
    if (t < off) red[t] += red[t + off];
    __syncthreads();
  }
  if (t == 0) atomicAdd(acc, (u64)red[0]);
}

__global__ void finalize_kernel(const u64* __restrict__ acc,
                                float* __restrict__ out, int npix) {
  s64 total = (s64)acc[0];
  out[0] = (float)(0.1 * (double)total / 2048.0 / (3.0 * (double)npix));
}

extern "C" void kernel_launch(void* const* d_in, const int* in_sizes, int n_in,
                              void* d_out, int out_size, void* d_ws, size_t ws_size,
                              hipStream_t stream) {
  const float* fake = (const float*)d_in[0];
  const float* refb = (const float*)d_in[1];
  const int* ma = (const int*)d_in[2];
  const int* mb = (const int*)d_in[3];
  const int npix = in_sizes[2];  // H*W

  u64* gNS = (u64*)d_ws;                                // [8][12][512] u64
  u64* gT = (u64*)((char*)d_ws + 393216);               // [8][12][128] u64
  u64* acc = (u64*)((char*)d_ws + 491520);              // s64
  float* out = (float*)d_out;

  hipMemsetAsync(d_ws, 0, 491528, stream);
  // 62.5 KB LDS/block -> 2 blocks/CU (one src + one tar block per CU).
  hist_kernel<<<512, 1024, 0, stream>>>(fake, refb, ma, mb, gNS, gT, npix);
  cdf_loss_kernel<<<12, 256, 0, stream>>>(gNS, gT, acc);
  finalize_kernel<<<1, 1, 0, stream>>>(acc, out, npix);
}